// Round 2
// baseline (4381.407 us; speedup 1.0000x reference)
//
#include <hip/hip_runtime.h>
#include <stdint.h>

#define NB 512     // batch
#define NH 512     // hidden
#define NG 2048    // 4*H
#define NF 32      // input features
#define NS 64      // seq len / output steps
#define NO 32      // output dim

typedef __attribute__((ext_vector_type(8))) short bf16x8;
typedef __attribute__((ext_vector_type(8))) unsigned short u16x8;
typedef __attribute__((ext_vector_type(16))) float f32x16;

__device__ __forceinline__ float sigf(float x) { return 1.f / (1.f + __expf(-x)); }
__device__ __forceinline__ float tanh_(float x) { return 1.f - 2.f / (1.f + __expf(2.f * x)); }

// bf16 RNE convert on raw bits (finite values only)
__device__ __forceinline__ unsigned short f2bf(float f) {
  uint32_t u = __float_as_uint(f);
  u = (u + 0x7FFFu + ((u >> 16) & 1u)) >> 16;
  return (unsigned short)u;
}
__device__ __forceinline__ float bf2f(unsigned short u) {
  return __uint_as_float(((uint32_t)u) << 16);
}

// ---------------- zero: c (1MB f32) + h0_hi/h0_lo (0.5MB each) contiguous ----------------
__global__ __launch_bounds__(256)
void zero_k(float* __restrict__ p) {
  int i = (blockIdx.x * 256 + threadIdx.x) * 4;   // 524288 floats total
  float4 z = make_float4(0.f, 0.f, 0.f, 0.f);
  *(float4*)&p[i] = z;
}

// ---------------- prep: WhT_p (plain) and WhpT_p (folded) transposed+permuted+split ----
// out[q][k], q = j*4+gate (gate-interleaved), k = hidden. 256 blocks = 8 kt x 32 qt.
__global__ __launch_bounds__(256)
void prep_w_k(const float* __restrict__ Wh, const float* __restrict__ Wd,
              const float* __restrict__ Wx,
              unsigned short* __restrict__ WhT_hi, unsigned short* __restrict__ WhT_lo,
              unsigned short* __restrict__ WhpT_hi, unsigned short* __restrict__ WhpT_lo)
{
  __shared__ float T[64][68];
  __shared__ float Wds[64][32];
  __shared__ float Wxs[32][64];
  const int tid = threadIdx.x;
  const int kt = (int)blockIdx.x >> 5;
  const int qt = (int)blockIdx.x & 31;
  const int k0 = kt * 64;
  const int jb = qt * 16;

  #pragma unroll
  for (int g = 0; g < 4; ++g) {
    for (int it = 0; it < 4; ++it) {
      int e = tid + it * 256;              // 0..1023
      int r = e >> 4, jj = e & 15;
      T[r][jj * 4 + g] = Wh[(size_t)(k0 + r) * NG + g * NH + jb + jj];
    }
  }
  for (int it = 0; it < 8; ++it) {
    int e = tid + it * 256;                // 0..2047
    int r = e >> 5, o = e & 31;
    Wds[r][o] = Wd[(size_t)(k0 + r) * NO + o];
  }
  for (int it = 0; it < 8; ++it) {
    int e = tid + it * 256;
    int o = e >> 6, q = e & 63;
    Wxs[o][q] = Wx[(size_t)o * NG + (q & 3) * NH + jb + (q >> 2)];
  }
  __syncthreads();
  const int q = tid >> 2, kq = tid & 3;
  for (int i = 0; i < 16; ++i) {
    int kk = kq * 16 + i;
    float v = T[kk][q];
    float fold = 0.f;
    #pragma unroll
    for (int o = 0; o < 32; ++o) fold += Wds[kk][o] * Wxs[o][q];
    float vp = v + fold;
    size_t oidx = (size_t)(qt * 64 + q) * NH + k0 + kk;
    unsigned short h1 = f2bf(v);
    WhT_hi[oidx] = h1;  WhT_lo[oidx] = f2bf(v - bf2f(h1));
    unsigned short h2 = f2bf(vp);
    WhpT_hi[oidx] = h2; WhpT_lo[oidx] = f2bf(vp - bf2f(h2));
  }
}

// ---------------- prep: WxT_p [2048][32] split ----------------
__global__ __launch_bounds__(256)
void prep_wx_k(const float* __restrict__ Wx,
               unsigned short* __restrict__ hi, unsigned short* __restrict__ lo) {
  int e = blockIdx.x * 256 + threadIdx.x;    // 65536
  int q = e >> 5, k = e & 31;
  float v = Wx[(size_t)k * NG + (q & 3) * NH + (q >> 2)];
  unsigned short h = f2bf(v);
  hi[(size_t)q * NF + k] = h;
  lo[(size_t)q * NF + k] = f2bf(v - bf2f(h));
}

// ---------------- prep: permuted biases (plain + folded) ----------------
__global__ __launch_bounds__(256)
void prep_bias_k(const float* __restrict__ b, const float* __restrict__ bd,
                 const float* __restrict__ Wx, float* __restrict__ b_p,
                 float* __restrict__ bp_p) {
  int q = blockIdx.x * 256 + threadIdx.x;
  int g = (q & 3) * NH + (q >> 2);
  float v = b[g];
  float f = v;
  #pragma unroll
  for (int o = 0; o < 32; ++o) f += bd[o] * Wx[(size_t)o * NG + g];
  b_p[q] = v; bp_p[q] = f;
}

// ---------------- prep: split x into bf16 hi/lo ----------------
__global__ __launch_bounds__(256)
void prep_x_k(const float* __restrict__ x, unsigned short* __restrict__ hi,
              unsigned short* __restrict__ lo) {
  int e = (blockIdx.x * 256 + threadIdx.x) * 4;   // 1048576 floats
  float4 v = *(const float4*)&x[e];
  unsigned short h0 = f2bf(v.x), h1 = f2bf(v.y), h2 = f2bf(v.z), h3 = f2bf(v.w);
  ushort4 hv = make_ushort4(h0, h1, h2, h3);
  ushort4 lv = make_ushort4(f2bf(v.x - bf2f(h0)), f2bf(v.y - bf2f(h1)),
                            f2bf(v.z - bf2f(h2)), f2bf(v.w - bf2f(h3)));
  *(ushort4*)&hi[e] = hv;
  *(ushort4*)&lo[e] = lv;
}

// ---------------- fused LSTM step: Z = [h|x] @ W via bf16x3-split MFMA ----------------
// Grid 256 = 8 rowblocks x 32 colblocks (blockIdx = rb*32+cb so XCD = cb%8 -> B L2-resident).
// Tile 64 rows x 64 permuted cols (16 j x 4 gates). 4 waves as 2x2, each 32x32 via
// mfma_f32_32x32x16_bf16 (3 MFMAs per k16: Ah*Bh + Ah*Bl + Al*Bh).
// LDS tiles [64 rows][64 k] bf16, XOR-swizzled 16B slots (slot = kg ^ (row&7)).
// Epilogue: Z -> LDS -> per-(row,j) gate math -> c (f32) and h (bf16 hi/lo split).
// EMIT_PRED: pred_{s_out} = h_in @ Wd + bd for o = cb (K 4-way split + LDS reduce).
template<bool HAS_X, bool EMIT_PRED>
__global__ __launch_bounds__(256)
void lstm_step_k(const unsigned short* __restrict__ hin_hi, const unsigned short* __restrict__ hin_lo,
                 float* __restrict__ c_st,
                 unsigned short* __restrict__ hout_hi, unsigned short* __restrict__ hout_lo,
                 const unsigned short* __restrict__ WT_hi, const unsigned short* __restrict__ WT_lo,
                 const float* __restrict__ bias_p,
                 const unsigned short* __restrict__ x_hi, const unsigned short* __restrict__ x_lo,
                 const unsigned short* __restrict__ WxT_hi, const unsigned short* __restrict__ WxT_lo,
                 const float* __restrict__ Wd, const float* __restrict__ bd,
                 float* __restrict__ out, int s_out, int t)
{
  __shared__ __attribute__((aligned(16))) unsigned short As_hi[2][4096];
  __shared__ __attribute__((aligned(16))) unsigned short As_lo[2][4096];
  __shared__ __attribute__((aligned(16))) unsigned short Bs_hi[2][4096];
  __shared__ __attribute__((aligned(16))) unsigned short Bs_lo[2][4096];
  __shared__ float Zs[64][68];
  __shared__ float red[4][64];

  const int tid = threadIdx.x;
  const int lane = tid & 63;
  const int wv = tid >> 6;
  const int wr = wv >> 1, wc = wv & 1;
  const int rb = (int)blockIdx.x >> 5, cb = (int)blockIdx.x & 31;
  const int rowBase = rb * 64, qBase = cb * 64, jBase = cb * 16;

  // staging: each thread moves 2x16B per tile (4 tiles: Ah, Al, Bh, Bl)
  const int srow = tid >> 3;                    // 0..31 (and +32)
  const int skg = tid & 7;
  const int sslot = (skg ^ (srow & 7)) << 3;    // (row+32)&7 == row&7
  const size_t aoff0 = (size_t)(rowBase + srow) * NH + skg * 8;
  const size_t aoff1 = aoff0 + (size_t)32 * NH;
  const size_t boff0 = (size_t)(qBase + srow) * NH + skg * 8;
  const size_t boff1 = boff0 + (size_t)32 * NH;
  const int l0 = srow * 64 + sslot;
  const int l1 = (srow + 32) * 64 + sslot;

  float4 ld[8];
  auto LOADS = [&](int k0) {
    ld[0] = *(const float4*)&hin_hi[aoff0 + k0];
    ld[1] = *(const float4*)&hin_lo[aoff0 + k0];
    ld[2] = *(const float4*)&WT_hi[boff0 + k0];
    ld[3] = *(const float4*)&WT_lo[boff0 + k0];
    ld[4] = *(const float4*)&hin_hi[aoff1 + k0];
    ld[5] = *(const float4*)&hin_lo[aoff1 + k0];
    ld[6] = *(const float4*)&WT_hi[boff1 + k0];
    ld[7] = *(const float4*)&WT_lo[boff1 + k0];
  };
  auto WRITES = [&](int b) {
    *(float4*)&As_hi[b][l0] = ld[0];
    *(float4*)&As_lo[b][l0] = ld[1];
    *(float4*)&Bs_hi[b][l0] = ld[2];
    *(float4*)&Bs_lo[b][l0] = ld[3];
    *(float4*)&As_hi[b][l1] = ld[4];
    *(float4*)&As_lo[b][l1] = ld[5];
    *(float4*)&Bs_hi[b][l1] = ld[6];
    *(float4*)&Bs_lo[b][l1] = ld[7];
  };

  // x staging: tiles [64][32], one 16B per thread per tile
  const int xrow = tid >> 2;                    // 0..63
  const int xkg = tid & 3;
  const int xslot = (xkg ^ (xrow & 3)) << 3;
  auto LOADX = [&]() {
    if (HAS_X) {
      ld[0] = *(const float4*)&x_hi[(size_t)(rowBase + xrow) * (NS * NF) + t * NF + xkg * 8];
      ld[1] = *(const float4*)&x_lo[(size_t)(rowBase + xrow) * (NS * NF) + t * NF + xkg * 8];
      ld[2] = *(const float4*)&WxT_hi[(size_t)(qBase + xrow) * NF + xkg * 8];
      ld[3] = *(const float4*)&WxT_lo[(size_t)(qBase + xrow) * NF + xkg * 8];
    }
  };
  auto WRITEX = [&](int b) {
    if (HAS_X) {
      *(float4*)&As_hi[b][xrow * 32 + xslot] = ld[0];
      *(float4*)&As_lo[b][xrow * 32 + xslot] = ld[1];
      *(float4*)&Bs_hi[b][xrow * 32 + xslot] = ld[2];
      *(float4*)&Bs_lo[b][xrow * 32 + xslot] = ld[3];
    }
  };

  f32x16 acc;
  #pragma unroll
  for (int i = 0; i < 16; ++i) acc[i] = 0.f;

  const int Ar = wr * 32 + (lane & 31);
  const int Br = wc * 32 + (lane & 31);
  const int kgl = lane >> 5;
  const int arow = Ar * 64, brow = Br * 64;
  const int am = Ar & 7, bm = Br & 7;

  auto COMPUTE = [&](int b) {
    #pragma unroll
    for (int ki = 0; ki < 4; ++ki) {
      int kg = ki * 2 + kgl;
      bf16x8 ah = *(const bf16x8*)&As_hi[b][arow + ((kg ^ am) << 3)];
      bf16x8 al = *(const bf16x8*)&As_lo[b][arow + ((kg ^ am) << 3)];
      bf16x8 bh = *(const bf16x8*)&Bs_hi[b][brow + ((kg ^ bm) << 3)];
      bf16x8 bl = *(const bf16x8*)&Bs_lo[b][brow + ((kg ^ bm) << 3)];
      acc = __builtin_amdgcn_mfma_f32_32x32x16_bf16(ah, bh, acc, 0, 0, 0);
      acc = __builtin_amdgcn_mfma_f32_32x32x16_bf16(ah, bl, acc, 0, 0, 0);
      acc = __builtin_amdgcn_mfma_f32_32x32x16_bf16(al, bh, acc, 0, 0, 0);
    }
  };
  auto COMPUTEX = [&](int b) {
    #pragma unroll
    for (int ki = 0; ki < 2; ++ki) {
      int kg = ki * 2 + kgl;
      bf16x8 ah = *(const bf16x8*)&As_hi[b][Ar * 32 + ((kg ^ (Ar & 3)) << 3)];
      bf16x8 al = *(const bf16x8*)&As_lo[b][Ar * 32 + ((kg ^ (Ar & 3)) << 3)];
      bf16x8 bh = *(const bf16x8*)&Bs_hi[b][Br * 32 + ((kg ^ (Br & 3)) << 3)];
      bf16x8 bl = *(const bf16x8*)&Bs_lo[b][Br * 32 + ((kg ^ (Br & 3)) << 3)];
      acc = __builtin_amdgcn_mfma_f32_32x32x16_bf16(ah, bh, acc, 0, 0, 0);
      acc = __builtin_amdgcn_mfma_f32_32x32x16_bf16(ah, bl, acc, 0, 0, 0);
      acc = __builtin_amdgcn_mfma_f32_32x32x16_bf16(al, bh, acc, 0, 0, 0);
    }
  };

  // main loop: prefetch chunk k+1 into regs, compute chunk k, write k+1 to other buffer
  LOADS(0);
  WRITES(0);
  __syncthreads();
  int buf = 0;
  for (int ch = 0; ch < 8; ++ch) {
    if (ch < 7) LOADS((ch + 1) * 64);
    else LOADX();
    COMPUTE(buf);
    if (ch < 7) WRITES(buf ^ 1);
    else WRITEX(buf ^ 1);
    __syncthreads();
    buf ^= 1;
  }
  if (HAS_X) COMPUTEX(buf);

  // ---- Z -> LDS ----
  #pragma unroll
  for (int r = 0; r < 16; ++r) {
    int R = wr * 32 + ((lane >> 5) << 2) + (r & 3) + ((r >> 2) << 3);
    Zs[R][wc * 32 + (lane & 31)] = acc[r];
  }
  __syncthreads();

  // ---- cell update: thread -> (row, 4 j's) ----
  {
    const int row = tid >> 2, jq = tid & 3;
    const int jg = jBase + jq * 4;
    const size_t cidx = (size_t)(rowBase + row) * NH + jg;
    float4 cold = *(const float4*)&c_st[cidx];
    float cv[4] = { cold.x, cold.y, cold.z, cold.w };
    float cn[4], hn[4];
    #pragma unroll
    for (int jj = 0; jj < 4; ++jj) {
      float4 z = *(const float4*)&Zs[row][jq * 16 + jj * 4];
      const float* bp = &bias_p[qBase + jq * 16 + jj * 4];
      float zi = z.x + bp[0], zf = z.y + bp[1], zg = z.z + bp[2], zo = z.w + bp[3];
      float ig = sigf(zi), fg = sigf(zf), gg = tanh_(zg), og = sigf(zo);
      float cnew = fg * cv[jj] + ig * gg;
      cn[jj] = cnew;
      hn[jj] = og * tanh_(cnew);
    }
    *(float4*)&c_st[cidx] = make_float4(cn[0], cn[1], cn[2], cn[3]);
    unsigned short hh[4], hl[4];
    #pragma unroll
    for (int jj = 0; jj < 4; ++jj) {
      hh[jj] = f2bf(hn[jj]);
      hl[jj] = f2bf(hn[jj] - bf2f(hh[jj]));
    }
    *(ushort4*)&hout_hi[cidx] = make_ushort4(hh[0], hh[1], hh[2], hh[3]);
    *(ushort4*)&hout_lo[cidx] = make_ushort4(hl[0], hl[1], hl[2], hl[3]);
  }

  // ---- pred_{s_out}[rows][o=cb] = h_in @ Wd + bd ----
  if (EMIT_PRED) {
    const int prow = tid & 63, ks = tid >> 6;
    const int o = cb;
    const unsigned short* ph = &hin_hi[(size_t)(rowBase + prow) * NH + ks * 128];
    const unsigned short* pl = &hin_lo[(size_t)(rowBase + prow) * NH + ks * 128];
    const float* wd = &Wd[(size_t)(ks * 128) * NO + o];
    float p = 0.f;
    #pragma unroll 4
    for (int q8 = 0; q8 < 16; ++q8) {
      u16x8 hv = *(const u16x8*)&ph[q8 * 8];
      u16x8 lv = *(const u16x8*)&pl[q8 * 8];
      #pragma unroll
      for (int e = 0; e < 8; ++e)
        p += (bf2f(hv[e]) + bf2f(lv[e])) * wd[(q8 * 8 + e) * NO];
    }
    red[ks][prow] = p;
    __syncthreads();
    if (tid < 64) {
      float s = red[0][tid] + red[1][tid] + red[2][tid] + red[3][tid] + bd[o];
      out[((size_t)(rowBase + tid) * NS + s_out) * NO + o] = s;
    }
  }
}

// ---------------- final pred_63 ----------------
__global__ __launch_bounds__(256)
void final_pred_k(const unsigned short* __restrict__ h_hi, const unsigned short* __restrict__ h_lo,
                  const float* __restrict__ Wd, const float* __restrict__ bd,
                  float* __restrict__ out)
{
  __shared__ float red[4][64];
  const int tid = threadIdx.x;
  const int rb = (int)blockIdx.x >> 5, o = (int)blockIdx.x & 31;
  const int rowBase = rb * 64;
  const int prow = tid & 63, ks = tid >> 6;
  const unsigned short* ph = &h_hi[(size_t)(rowBase + prow) * NH + ks * 128];
  const unsigned short* pl = &h_lo[(size_t)(rowBase + prow) * NH + ks * 128];
  const float* wd = &Wd[(size_t)(ks * 128) * NO + o];
  float p = 0.f;
  #pragma unroll 4
  for (int q8 = 0; q8 < 16; ++q8) {
    u16x8 hv = *(const u16x8*)&ph[q8 * 8];
    u16x8 lv = *(const u16x8*)&pl[q8 * 8];
    #pragma unroll
    for (int e = 0; e < 8; ++e)
      p += (bf2f(hv[e]) + bf2f(lv[e])) * wd[(q8 * 8 + e) * NO];
  }
  red[ks][prow] = p;
  __syncthreads();
  if (tid < 64) {
    float s = red[0][tid] + red[1][tid] + red[2][tid] + red[3][tid] + bd[o];
    out[((size_t)(rowBase + tid) * NS + 63) * NO + o] = s;
  }
}

extern "C" void kernel_launch(void* const* d_in, const int* in_sizes, int n_in,
                              void* d_out, int out_size, void* d_ws, size_t ws_size,
                              hipStream_t stream) {
  (void)in_sizes; (void)n_in; (void)out_size; (void)ws_size;
  const float* x  = (const float*)d_in[0];   // (512, 64, 32)
  const float* Wx = (const float*)d_in[1];   // (32, 2048)
  const float* Wh = (const float*)d_in[2];   // (512, 2048)
  const float* b  = (const float*)d_in[3];   // (2048,)
  const float* Wd = (const float*)d_in[4];   // (512, 32)
  const float* bd = (const float*)d_in[5];   // (32,)
  float* out = (float*)d_out;                // (512, 64, 32)

  char* w = (char*)d_ws;                     // 15.27 MB used
  float* c = (float*)w;                                        // 1 MB
  unsigned short* hA_hi  = (unsigned short*)(w + 1048576);     // 0.5 MB
  unsigned short* hA_lo  = (unsigned short*)(w + 1572864);
  unsigned short* hB_hi  = (unsigned short*)(w + 2097152);
  unsigned short* hB_lo  = (unsigned short*)(w + 2621440);
  unsigned short* WhT_hi = (unsigned short*)(w + 3145728);     // 2 MB each
  unsigned short* WhT_lo = (unsigned short*)(w + 5242880);
  unsigned short* WhpT_hi= (unsigned short*)(w + 7340032);
  unsigned short* WhpT_lo= (unsigned short*)(w + 9437184);
  unsigned short* WxT_hi = (unsigned short*)(w + 11534336);    // 128 KB each
  unsigned short* WxT_lo = (unsigned short*)(w + 11665408);
  float* b_p  = (float*)(w + 11796480);                        // 8 KB each
  float* bp_p = (float*)(w + 11804672);
  unsigned short* x_hi = (unsigned short*)(w + 11812864);      // 2 MB each
  unsigned short* x_lo = (unsigned short*)(w + 13910016);

  zero_k<<<512, 256, 0, stream>>>((float*)w);   // c + hA_hi + hA_lo
  prep_w_k<<<256, 256, 0, stream>>>(Wh, Wd, Wx, WhT_hi, WhT_lo, WhpT_hi, WhpT_lo);
  prep_wx_k<<<256, 256, 0, stream>>>(Wx, WxT_hi, WxT_lo);
  prep_bias_k<<<8, 256, 0, stream>>>(b, bd, Wx, b_p, bp_p);
  prep_x_k<<<1024, 256, 0, stream>>>(x, x_hi, x_lo);

  unsigned short* hi[2] = { hA_hi, hB_hi };
  unsigned short* lo[2] = { hA_lo, hB_lo };
  int p = 0;
  for (int tt = 0; tt < 64; ++tt) {
    lstm_step_k<true, false><<<256, 256, 0, stream>>>(
        hi[p], lo[p], c, hi[p ^ 1], lo[p ^ 1],
        WhT_hi, WhT_lo, b_p, x_hi, x_lo, WxT_hi, WxT_lo,
        nullptr, nullptr, nullptr, 0, tt);
    p ^= 1;
  }
  for (int s = 1; s < 64; ++s) {
    lstm_step_k<false, true><<<256, 256, 0, stream>>>(
        hi[p], lo[p], c, hi[p ^ 1], lo[p ^ 1],
        WhpT_hi, WhpT_lo, bp_p, nullptr, nullptr, nullptr, nullptr,
        Wd, bd, out, s - 1, 0);
    p ^= 1;
  }
  final_pred_k<<<256, 256, 0, stream>>>(hi[p], lo[p], Wd, bd, out);
}

// Round 3
// 1306.352 us; speedup vs baseline: 3.3539x; 3.3539x over previous
//
#include <hip/hip_runtime.h>
#include <stdint.h>

#define NB 512     // batch
#define NH 512     // hidden
#define NG 2048    // 4*H
#define NF 32      // input features
#define NS 64      // seq len / output steps
#define NO 32      // output dim

typedef unsigned short ushort_t;
typedef __attribute__((ext_vector_type(8))) short bf16x8;
typedef __attribute__((ext_vector_type(8))) unsigned short u16x8;
typedef __attribute__((ext_vector_type(16))) float f32x16;

__device__ __forceinline__ float sigf(float x) { return 1.f / (1.f + __expf(-x)); }
__device__ __forceinline__ float tanh_(float x) { return 1.f - 2.f / (1.f + __expf(2.f * x)); }

__device__ __forceinline__ unsigned short f2bf(float f) {
  uint32_t u = __float_as_uint(f);
  u = (u + 0x7FFFu + ((u >> 16) & 1u)) >> 16;
  return (unsigned short)u;
}
__device__ __forceinline__ float bf2f(unsigned short u) {
  return __uint_as_float(((uint32_t)u) << 16);
}

// ---------------- zero: c (1MB) + hpkA (1MB) contiguous ----------------
__global__ __launch_bounds__(256)
void zero_k(float* __restrict__ p) {
  int i = (blockIdx.x * 256 + threadIdx.x) * 4;   // 524288 floats
  *(float4*)&p[i] = make_float4(0.f, 0.f, 0.f, 0.f);
}

// ---------------- prep: pack Wh (plain) and Wh+Wd@Wx (folded) into MFMA frag order ----
// Layout: [cb(32)][qh(2)][kh(2)][s(16)][part(2)][lane(64)][e(8)] bf16.
// Element: k = kh*256+s*16+(lane>>5)*8+e ; q = cb*64+qh*32+(lane&31); col=(q&3)*NH+(q>>2).
// One block per (cb,qh,kh,s) = 2048 blocks; emits 1024 bf16 to each array.
__global__ __launch_bounds__(256)
void prep_w_k(const float* __restrict__ Wh, const float* __restrict__ Wd,
              const float* __restrict__ Wx,
              ushort_t* __restrict__ Wpk, ushort_t* __restrict__ Wppk)
{
  __shared__ float Whs[16][33];
  __shared__ float Folds[16][33];
  __shared__ float Wds[16][32];
  __shared__ float Wxs[32][33];
  const int p = blockIdx.x;
  const int s = p & 15, kh = (p >> 4) & 1, qh = (p >> 5) & 1, cb = p >> 6;
  const int k0 = kh * 256 + s * 16;
  const int tid = threadIdx.x;

  for (int it = 0; it < 2; ++it) {
    int i = it * 256 + tid; int kl = i >> 5, o = i & 31;
    Wds[kl][o] = Wd[(size_t)(k0 + kl) * NO + o];
  }
  for (int it = 0; it < 4; ++it) {
    int i = it * 256 + tid; int o = i >> 5, ql = i & 31;
    int q = cb * 64 + qh * 32 + ql;
    int col = (q & 3) * NH + (q >> 2);
    Wxs[o][ql] = Wx[(size_t)o * NG + col];
  }
  for (int it = 0; it < 2; ++it) {
    int i = it * 256 + tid; int kl = i >> 5, ql = i & 31;
    int q = cb * 64 + qh * 32 + ql;
    int col = (q & 3) * NH + (q >> 2);
    Whs[kl][ql] = Wh[(size_t)(k0 + kl) * NG + col];
  }
  __syncthreads();
  for (int it = 0; it < 2; ++it) {
    int i = it * 256 + tid; int kl = i >> 5, ql = i & 31;
    float f = 0.f;
    #pragma unroll
    for (int o = 0; o < 32; ++o) f += Wds[kl][o] * Wxs[o][ql];
    Folds[kl][ql] = Whs[kl][ql] + f;
  }
  __syncthreads();
  const size_t base = (size_t)p * 1024;
  for (int it = 0; it < 4; ++it) {
    int i = it * 256 + tid;             // part*512 + l*8 + e
    int part = i >> 9, l = (i >> 3) & 63, e = i & 7;
    int kl = (l >> 5) * 8 + e;
    int ql = l & 31;
    float v = Whs[kl][ql], vf = Folds[kl][ql];
    unsigned short o1, o2;
    if (part == 0) { o1 = f2bf(v); o2 = f2bf(vf); }
    else {
      o1 = f2bf(v - bf2f(f2bf(v)));
      o2 = f2bf(vf - bf2f(f2bf(vf)));
    }
    Wpk[base + i] = o1;
    Wppk[base + i] = o2;
  }
}

// ---------------- prep: pack Wx into frag order [cb][qh][kh][part][lane][e] ----------------
__global__ __launch_bounds__(256)
void prep_wx_k(const float* __restrict__ Wx, ushort_t* __restrict__ Wxpk) {
  size_t i0 = ((size_t)blockIdx.x * 256 + threadIdx.x) * 4;   // 131072 total
  int e0 = (int)(i0 & 7);
  int l = (int)((i0 >> 3) & 63);
  int part = (int)((i0 >> 9) & 1);
  int kh = (int)((i0 >> 10) & 1);
  int qh = (int)((i0 >> 11) & 1);
  int cb = (int)(i0 >> 12);
  int q = cb * 64 + qh * 32 + (l & 31);
  int col = (q & 3) * NH + (q >> 2);
  unsigned short r[4];
  #pragma unroll
  for (int d = 0; d < 4; ++d) {
    int f = kh * 16 + (l >> 5) * 8 + e0 + d;
    float v = Wx[(size_t)f * NG + col];
    unsigned short h = f2bf(v);
    r[d] = part ? f2bf(v - bf2f(h)) : h;
  }
  *(ushort4*)&Wxpk[i0] = make_ushort4(r[0], r[1], r[2], r[3]);
}

// ---------------- prep: pack x into frag order [t][rb][kh][part][lane][e] ----------------
__global__ __launch_bounds__(256)
void prep_x_k(const float* __restrict__ x, ushort_t* __restrict__ xpk) {
  size_t i0 = ((size_t)blockIdx.x * 256 + threadIdx.x) * 4;   // 2^21 total
  int e0 = (int)(i0 & 7);
  int l = (int)((i0 >> 3) & 63);
  int part = (int)((i0 >> 9) & 1);
  int kh = (int)((i0 >> 10) & 1);
  int rb = (int)((i0 >> 11) & 15);
  int t = (int)(i0 >> 15);
  int row = rb * 32 + (l & 31);
  int f = kh * 16 + (l >> 5) * 8 + e0;
  float4 v = *(const float4*)&x[(size_t)row * (NS * NF) + t * NF + f];
  float vv[4] = { v.x, v.y, v.z, v.w };
  unsigned short r[4];
  #pragma unroll
  for (int d = 0; d < 4; ++d) {
    unsigned short h = f2bf(vv[d]);
    r[d] = part ? f2bf(vv[d] - bf2f(h)) : h;
  }
  *(ushort4*)&xpk[i0] = make_ushort4(r[0], r[1], r[2], r[3]);
}

// ---------------- prep: permuted biases (plain + folded) ----------------
__global__ __launch_bounds__(256)
void prep_bias_k(const float* __restrict__ b, const float* __restrict__ bd,
                 const float* __restrict__ Wx, float* __restrict__ b_p,
                 float* __restrict__ bp_p) {
  int q = blockIdx.x * 256 + threadIdx.x;
  int g = (q & 3) * NH + (q >> 2);
  float v = b[g];
  float f = v;
  #pragma unroll
  for (int o = 0; o < 32; ++o) f += bd[o] * Wx[(size_t)o * NG + g];
  b_p[q] = v; bp_p[q] = f;
}

// ---------------- fused LSTM step: barrier-free register-streamed MFMA ----------------
// h state lives in PACKED fragment layout [rb(16)][kh(2)][s(16)][part(2)][lane(64)][e(8)].
// Grid 512 = 16 rb x 32 cb (XCD = cb%8). Block 256 = 4 waves: (qh = wv&1, kh = wv>>1).
// Each wave: 32 rows x 32 q, K-half of 256 (16 k-steps), 3 MFMAs/step (Ah*Bh+Ah*Bl+Al*Bh).
// 4-deep register pipeline, no LDS/barriers in the K loop. K-split reduced via Zs.
template<bool HAS_X, bool EMIT_PRED>
__global__ __launch_bounds__(256, 2)
void lstm_step_k(const ushort_t* __restrict__ hin,   // packed
                 float* __restrict__ c_st,
                 ushort_t* __restrict__ hout,        // packed
                 const ushort_t* __restrict__ Wpk,
                 const float* __restrict__ bias_p,
                 const ushort_t* __restrict__ xpk,
                 const ushort_t* __restrict__ Wxpk,
                 const float* __restrict__ Wd, const float* __restrict__ bd,
                 float* __restrict__ out, int s_out, int t)
{
  __shared__ float Zs[2][64][33];
  __shared__ float red[8][32];
  __shared__ float wdcol[512];

  const int tid = threadIdx.x;
  const int lane = tid & 63;
  const int wv = tid >> 6;
  const int qh = wv & 1, kh = wv >> 1;
  const int rb = (int)blockIdx.x >> 5, cb = (int)blockIdx.x & 31;
  const int rowBase = rb * 32, qBase = cb * 64, jBase = cb * 16;

  if (EMIT_PRED) {
    wdcol[tid] = Wd[(size_t)tid * NO + cb];
    wdcol[256 + tid] = Wd[(size_t)(256 + tid) * NO + cb];
  }

  const ushort_t* Abase = hin + (size_t)(rb * 2 + kh) * 16 * 1024 + lane * 8;
  const ushort_t* Bbase = Wpk + (size_t)((cb * 2 + qh) * 2 + kh) * 16 * 1024 + lane * 8;

  f32x16 acc;
  #pragma unroll
  for (int i = 0; i < 16; ++i) acc[i] = 0.f;

  bf16x8 ah[4], al[4], bh[4], bl[4];
  constexpr int NST = HAS_X ? 17 : 16;

  auto LD = [&](int ls) {
    const int bi = ls & 3;
    const ushort_t *pa, *pb;
    if (!HAS_X || ls < 16) {
      pa = Abase + ls * 1024;
      pb = Bbase + ls * 1024;
    } else {
      pa = xpk + (size_t)((t * 16 + rb) * 2 + kh) * 1024 + lane * 8;
      pb = Wxpk + (size_t)((cb * 2 + qh) * 2 + kh) * 1024 + lane * 8;
    }
    ah[bi] = *(const bf16x8*)pa;
    al[bi] = *(const bf16x8*)(pa + 512);
    bh[bi] = *(const bf16x8*)pb;
    bl[bi] = *(const bf16x8*)(pb + 512);
  };

  LD(0); LD(1); LD(2);
  #pragma unroll
  for (int s = 0; s < NST; ++s) {
    if (s + 3 < NST) LD(s + 3);
    const int bi = s & 3;
    acc = __builtin_amdgcn_mfma_f32_32x32x16_bf16(ah[bi], bh[bi], acc, 0, 0, 0);
    acc = __builtin_amdgcn_mfma_f32_32x32x16_bf16(ah[bi], bl[bi], acc, 0, 0, 0);
    acc = __builtin_amdgcn_mfma_f32_32x32x16_bf16(al[bi], bh[bi], acc, 0, 0, 0);
  }

  // ---- Z -> LDS (K-split halves kept separate; conflict-free stride-33) ----
  {
    const int ql = qh * 32 + (lane & 31);
    #pragma unroll
    for (int r = 0; r < 16; ++r) {
      int row = (r & 3) + 8 * (r >> 2) + 4 * (lane >> 5);
      Zs[kh][ql][row] = acc[r];
    }
  }
  __syncthreads();

  // ---- cell update: thread -> (row, 2 j's) ----
  {
    const int row = tid >> 3, jq = tid & 7;
    const size_t cidx = (size_t)(rowBase + row) * NH + jBase + jq * 2;
    float2 cold = *(const float2*)&c_st[cidx];
    float cv[2] = { cold.x, cold.y };
    float cn[2], hn[2];
    #pragma unroll
    for (int jj = 0; jj < 2; ++jj) {
      int jl = jq * 2 + jj;
      float4 bv = *(const float4*)&bias_p[qBase + jl * 4];
      float zi = Zs[0][jl * 4 + 0][row] + Zs[1][jl * 4 + 0][row] + bv.x;
      float zf = Zs[0][jl * 4 + 1][row] + Zs[1][jl * 4 + 1][row] + bv.y;
      float zg = Zs[0][jl * 4 + 2][row] + Zs[1][jl * 4 + 2][row] + bv.z;
      float zo = Zs[0][jl * 4 + 3][row] + Zs[1][jl * 4 + 3][row] + bv.w;
      float ig = sigf(zi), fg = sigf(zf), gg = tanh_(zg), og = sigf(zo);
      cn[jj] = fg * cv[jj] + ig * gg;
      hn[jj] = og * tanh_(cn[jj]);
    }
    *(float2*)&c_st[cidx] = make_float2(cn[0], cn[1]);
    const int lane_w = (jq >> 2) * 32 + row;
    const int e0 = (jq * 2) & 7;
    unsigned short hh[2], hl[2];
    #pragma unroll
    for (int jj = 0; jj < 2; ++jj) {
      hh[jj] = f2bf(hn[jj]);
      hl[jj] = f2bf(hn[jj] - bf2f(hh[jj]));
    }
    size_t hb = ((size_t)(rb * 2 + (cb >> 4)) * 16 + (cb & 15)) * 1024 + lane_w * 8 + e0;
    *(ushort2*)&hout[hb] = make_ushort2(hh[0], hh[1]);
    *(ushort2*)&hout[hb + 512] = make_ushort2(hl[0], hl[1]);
  }

  // ---- pred_{s_out}[rows][o=cb] = h_in @ Wd + bd (reads packed h) ----
  if (EMIT_PRED) {
    const int prow = tid & 31, ks = tid >> 5;
    const int khp = ks >> 2;
    float pacc = 0.f;
    #pragma unroll
    for (int c4 = 0; c4 < 4; ++c4) {
      int sch = (ks & 3) * 4 + c4;
      const ushort_t* base = hin + ((size_t)(rb * 2 + khp) * 16 + sch) * 1024;
      #pragma unroll
      for (int half = 0; half < 2; ++half) {
        u16x8 hv = *(const u16x8*)(base + (half * 32 + prow) * 8);
        u16x8 lv = *(const u16x8*)(base + 512 + (half * 32 + prow) * 8);
        int kb = khp * 256 + sch * 16 + half * 8;
        #pragma unroll
        for (int e = 0; e < 8; ++e)
          pacc += (bf2f(hv[e]) + bf2f(lv[e])) * wdcol[kb + e];
      }
    }
    red[ks][prow] = pacc;
    __syncthreads();
    if (tid < 32) {
      float ssum = red[0][tid] + red[1][tid] + red[2][tid] + red[3][tid]
                 + red[4][tid] + red[5][tid] + red[6][tid] + red[7][tid] + bd[cb];
      out[((size_t)(rowBase + tid) * NS + s_out) * NO + cb] = ssum;
    }
  }
}

// ---------------- final pred_63 from packed h ----------------
__global__ __launch_bounds__(256)
void final_pred_k(const ushort_t* __restrict__ hin, const float* __restrict__ Wd,
                  const float* __restrict__ bd, float* __restrict__ out)
{
  __shared__ float red[8][32];
  __shared__ float wdcol[512];
  const int tid = threadIdx.x;
  const int rb = (int)blockIdx.x >> 5, o = (int)blockIdx.x & 31;
  const int rowBase = rb * 32;
  wdcol[tid] = Wd[(size_t)tid * NO + o];
  wdcol[256 + tid] = Wd[(size_t)(256 + tid) * NO + o];
  __syncthreads();
  const int prow = tid & 31, ks = tid >> 5;
  const int khp = ks >> 2;
  float pacc = 0.f;
  #pragma unroll
  for (int c4 = 0; c4 < 4; ++c4) {
    int sch = (ks & 3) * 4 + c4;
    const ushort_t* base = hin + ((size_t)(rb * 2 + khp) * 16 + sch) * 1024;
    #pragma unroll
    for (int half = 0; half < 2; ++half) {
      u16x8 hv = *(const u16x8*)(base + (half * 32 + prow) * 8);
      u16x8 lv = *(const u16x8*)(base + 512 + (half * 32 + prow) * 8);
      int kb = khp * 256 + sch * 16 + half * 8;
      #pragma unroll
      for (int e = 0; e < 8; ++e)
        pacc += (bf2f(hv[e]) + bf2f(lv[e])) * wdcol[kb + e];
    }
  }
  red[ks][prow] = pacc;
  __syncthreads();
  if (tid < 32) {
    float ssum = red[0][tid] + red[1][tid] + red[2][tid] + red[3][tid]
               + red[4][tid] + red[5][tid] + red[6][tid] + red[7][tid] + bd[o];
    out[((size_t)(rowBase + tid) * NS + 63) * NO + o] = ssum;
  }
}

extern "C" void kernel_launch(void* const* d_in, const int* in_sizes, int n_in,
                              void* d_out, int out_size, void* d_ws, size_t ws_size,
                              hipStream_t stream) {
  (void)in_sizes; (void)n_in; (void)out_size; (void)ws_size;
  const float* x  = (const float*)d_in[0];   // (512, 64, 32)
  const float* Wx = (const float*)d_in[1];   // (32, 2048)
  const float* Wh = (const float*)d_in[2];   // (512, 2048)
  const float* b  = (const float*)d_in[3];   // (2048,)
  const float* Wd = (const float*)d_in[4];   // (512, 32)
  const float* bd = (const float*)d_in[5];   // (32,)
  float* out = (float*)d_out;                // (512, 64, 32)

  char* w = (char*)d_ws;                     // ~15.3 MB used
  float* c = (float*)w;                                   // 1 MB @ 0
  ushort_t* hpkA = (ushort_t*)(w + 1048576);              // 1 MB
  ushort_t* hpkB = (ushort_t*)(w + 2097152);              // 1 MB
  ushort_t* Wpk  = (ushort_t*)(w + 3145728);              // 4 MB
  ushort_t* Wppk = (ushort_t*)(w + 7340032);              // 4 MB
  ushort_t* Wxpk = (ushort_t*)(w + 11534336);             // 256 KB
  ushort_t* xpk  = (ushort_t*)(w + 11796480);             // 4 MB
  float* b_p  = (float*)(w + 15990784);                   // 8 KB
  float* bp_p = (float*)(w + 15998976);                   // 8 KB

  zero_k<<<512, 256, 0, stream>>>((float*)w);             // c + hpkA
  prep_w_k<<<2048, 256, 0, stream>>>(Wh, Wd, Wx, Wpk, Wppk);
  prep_wx_k<<<128, 256, 0, stream>>>(Wx, Wxpk);
  prep_x_k<<<2048, 256, 0, stream>>>(x, xpk);
  prep_bias_k<<<8, 256, 0, stream>>>(b, bd, Wx, b_p, bp_p);

  ushort_t* hb[2] = { hpkA, hpkB };
  int p = 0;
  for (int tt = 0; tt < 64; ++tt) {
    lstm_step_k<true, false><<<512, 256, 0, stream>>>(
        hb[p], c, hb[p ^ 1], Wpk, b_p, xpk, Wxpk,
        Wd, bd, nullptr, 0, tt);
    p ^= 1;
  }
  for (int s = 1; s < 64; ++s) {
    lstm_step_k<false, true><<<512, 256, 0, stream>>>(
        hb[p], c, hb[p ^ 1], Wppk, bp_p, nullptr, nullptr,
        Wd, bd, out, s - 1, 0);
    p ^= 1;
  }
  final_pred_k<<<512, 256, 0, stream>>>(hb[p], Wd, bd, out);
}